// Round 10
// baseline (206.201 us; speedup 1.0000x reference)
//
#include <hip/hip_runtime.h>
#include <math.h>

#define B_   8
#define C_   256
#define H_   64
#define W_   64
#define O_   256
#define KK_  9
#define CK_  2304      // C_*KK_
#define HW_  4096      // H_*W_
#define BN_EPS 1e-5f

typedef __bf16 bf16x8 __attribute__((ext_vector_type(8)));
typedef float  f32x4  __attribute__((ext_vector_type(4)));

static __device__ __forceinline__ unsigned short f2bf(float f) {   // RNE (weights)
    unsigned int u = __float_as_uint(f);
    unsigned int r = (u + 0x7fffu + ((u >> 16) & 1u)) >> 16;
    return (unsigned short)r;
}
// pack two f32 -> bf16x2 with round-half-up (2 adds + 1 v_perm)
static __device__ __forceinline__ unsigned int packbf2(float lo, float hi) {
    unsigned int ul = __float_as_uint(lo) + 0x8000u;
    unsigned int uh = __float_as_uint(hi) + 0x8000u;
    return __builtin_amdgcn_perm(uh, ul, 0x07060302u);
}
static __device__ __forceinline__ float bflo(unsigned int u) {
    return __uint_as_float(u << 16);
}
static __device__ __forceinline__ float bfhi(unsigned int u) {
    return __uint_as_float(u & 0xffff0000u);
}

// ---- kernel 0: prep. 2192 blocks x 256 thr.
//  blk <2048       : transpose x[b][c][hw] f32 -> xT[b][hw][c] bf16 (64c x 64hw tile)
//  blk 2048..2175  : repack w -> wKf  (B-frag order, LDS-staged, coalesced both sides)
//  blk 2176..2191  : repack w_off -> wof (same, o>=27 zero-padded)
__global__ __launch_bounds__(256) void prep_kernel(
    const float* __restrict__ x, const float* __restrict__ w,
    const float* __restrict__ w_off,
    unsigned short* __restrict__ xT, unsigned short* __restrict__ wKf,
    unsigned short* __restrict__ wof)
{
    __shared__ float tile[64][65];     // transpose staging
    __shared__ float wbuf[4608];       // weight staging (16 o x 288)

    const int blk = blockIdx.x;
    const int tid = threadIdx.x, lane = tid & 63, tg = tid >> 6;

    if (blk < 2048) {
        const int b   = blk & 7;
        const int ct  = (blk >> 3) & 3;
        const int hwt = blk >> 5;
        const int c0  = ct * 64, hw0 = hwt * 64;
        // stage 64c x 64hw tile (coalesced dword reads)
#pragma unroll
        for (int r = 0; r < 16; ++r) {
            int c_l = tg + r * 4;
            tile[c_l][lane] = x[((size_t)(b * C_ + c0 + c_l)) * HW_ + hw0 + lane];
        }
        __syncthreads();
        // write: 4 ch per lane packed -> uint2 (8B/lane, 512B/wave-instr)
#pragma unroll
        for (int it = 0; it < 4; ++it) {
            const int hw_l = tg * 16 + it * 4 + (lane >> 4);
            const int c_l4 = (lane & 15) * 4;
            float v0 = tile[c_l4 + 0][hw_l];
            float v1 = tile[c_l4 + 1][hw_l];
            float v2 = tile[c_l4 + 2][hw_l];
            float v3 = tile[c_l4 + 3][hw_l];
            uint2 pk;
            pk.x = packbf2(v0, v1);
            pk.y = packbf2(v2, v3);
            *(uint2*)&xT[((size_t)(b * HW_ + hw0 + hw_l)) * C_ + c0 + c_l4] = pk;
        }
    } else if (blk < 2176) {
        const int t2 = blk - 2048;
        const int NT = t2 >> 3, cb = t2 & 7;
        // stage w[NT*16..+16][cb*32..+32][0..9) = 16 x 288 contiguous floats per o
#pragma unroll
        for (int i = 0; i < 18; ++i) {
            int j = i * 256 + tid;
            int o_l = j / 288, rest = j - o_l * 288;
            wbuf[o_l * 288 + rest] = w[(size_t)(NT * 16 + o_l) * CK_ + cb * 288 + rest];
        }
        __syncthreads();
        // write dest-linear: 9 taps x 512 contiguous bf16 elems
#pragma unroll
        for (int i = 0; i < 18; ++i) {
            int d = i * 256 + tid;
            int tap = d >> 9, r5 = d & 511;
            int ln = r5 >> 3, e = r5 & 7;
            int n16 = ln & 15, q = ln >> 4;
            float val = wbuf[n16 * 288 + (q * 8 + e) * 9 + tap];
            wKf[((size_t)(NT * 72 + tap * 8 + cb) * 64 + ln) * 8 + e] = f2bf(val);
        }
    } else {
        const int t2 = blk - 2176;
        const int NT = t2 >> 3, cb = t2 & 7;
#pragma unroll
        for (int i = 0; i < 18; ++i) {
            int j = i * 256 + tid;
            int o_l = j / 288, rest = j - o_l * 288;
            int o = NT * 16 + o_l;
            wbuf[o_l * 288 + rest] =
                (o < 27) ? w_off[(size_t)o * CK_ + cb * 288 + rest] : 0.f;
        }
        __syncthreads();
#pragma unroll
        for (int i = 0; i < 18; ++i) {
            int d = i * 256 + tid;
            int tap = d >> 9, r5 = d & 511;
            int ln = r5 >> 3, e = r5 & 7;
            int n16 = ln & 15, q = ln >> 4;
            float val = wbuf[n16 * 288 + (q * 8 + e) * 9 + tap];
            wof[((size_t)(NT * 72 + tap * 8 + cb) * 64 + ln) * 8 + e] = f2bf(val);
        }
    }
}

// ---- kernel 1: fused offset-conv (MFMA, direct global A) + sample + MFMA GEMM + BN + ReLU
// grid 512 = (b = blk&7) x (h = blk>>3). 512 thr / 8 waves. LDS 51.2 KB -> 3 blocks/CU.
__global__ __launch_bounds__(512, 4) void dcn_fused_kernel(
    const unsigned short* __restrict__ xT, const unsigned short* __restrict__ wKf,
    const unsigned short* __restrict__ wof, const float* __restrict__ b_off,
    const float* __restrict__ bias, const float* __restrict__ gamma,
    const float* __restrict__ beta, const float* __restrict__ rmean,
    const float* __restrict__ rvar, float* __restrict__ out)
{
    // 0..9215      : wgtv[576] float4
    // 9216..18431  : idxv[576] int4
    // 18432..51199 : Abuf [8][4][64][8] bf16 (32 KB); omb[27][64] f32 aliases its start
    __shared__ __align__(16) unsigned char smem[51200];
    float4* wgtv = (float4*)smem;
    int4*   idxv = (int4*)(smem + 9216);
    typedef float OmbT[27][64];
    OmbT& omb = *(OmbT*)(smem + 18432);
    typedef unsigned short AbufT[8][4][64][8];
    AbufT& Abuf = *(AbufT*)(smem + 18432);

    const int blk = blockIdx.x;
    const int b = blk & 7, h = blk >> 3;
    const int tid = threadIdx.x, lane = tid & 63, wv = tid >> 6;
    const int m16 = lane & 15, q = lane >> 4;

    // ================= Phase A: offset conv, A-frags direct from global =================
    const int mi_a = wv & 3, nj_a = wv >> 2;
    const int pxa  = mi_a * 16 + m16;            // pixel 0..63 this lane covers
    f32x4 oacc = {0.f, 0.f, 0.f, 0.f};
    const uint4* wof4 = (const uint4*)wof;

#pragma unroll
    for (int r = 0; r < 3; ++r) {
        const int hh = h - 1 + r;
        if (hh < 0 || hh >= H_) continue;        // block-uniform
        const unsigned short* rowp = xT + ((size_t)(b * HW_ + hh * W_)) * C_ + q * 8;
#pragma unroll
        for (int s = 0; s < 3; ++s) {
            const int ww = pxa + s - 1;
            const bool ok = ((unsigned)ww) < (unsigned)W_;   // divergent at 1 lane max
            const unsigned short* pbase = rowp + ww * C_;
#pragma unroll
            for (int cc = 0; cc < 8; ++cc) {
                uint4 araw = ok ? *(const uint4*)(pbase + cc * 32)
                                : make_uint4(0u, 0u, 0u, 0u);
                uint4 braw = wof4[(size_t)(nj_a * 72 + (r * 3 + s) * 8 + cc) * 64 + lane];
                oacc = __builtin_amdgcn_mfma_f32_16x16x32_bf16(
                    __builtin_bit_cast(bf16x8, araw),
                    __builtin_bit_cast(bf16x8, braw), oacc, 0, 0, 0);
            }
        }
    }
    // phase-A epilogue: bias + sigmoid(mod) -> omb[t][px] (omb aliases Abuf)
    {
        const int t = nj_a * 16 + m16;
        if (t < 27) {
            const float bo = b_off[t];
            float s0 = oacc[0] + bo, s1 = oacc[1] + bo,
                  s2 = oacc[2] + bo, s3 = oacc[3] + bo;
            if (t >= 18) {
                s0 = 1.f / (1.f + expf(-s0));
                s1 = 1.f / (1.f + expf(-s1));
                s2 = 1.f / (1.f + expf(-s2));
                s3 = 1.f / (1.f + expf(-s3));
            }
            float4 rr; rr.x = s0; rr.y = s1; rr.z = s2; rr.w = s3;
            *(float4*)&omb[t][mi_a * 16 + q * 4] = rr;
        }
    }
    __syncthreads();                      // omb visible

    // ---- per-(pixel,tap) tables (wgtv/idxv disjoint from omb; no barrier in loop) ----
    for (int i = tid; i < 576; i += 512) {
        int p = i / 9, t = i - p * 9;
        float dy = omb[t][p];
        float dx = omb[t + 9][p];
        float md = omb[t + 18][p];
        float py = (float)(h - 1 + t / 3) + dy;
        float px = (float)(p - 1 + t % 3) + dx;
        float y0f = floorf(py), x0f = floorf(px);
        int   y0 = (int)y0f,    x0 = (int)x0f;
        float fy = py - y0f,    fx = px - x0f;
        int y0c = min(max(y0,     0), H_ - 1), y1c = min(max(y0 + 1, 0), H_ - 1);
        int x0c = min(max(x0,     0), W_ - 1), x1c = min(max(x0 + 1, 0), W_ - 1);
        float vy0 = (y0     >= 0 && y0     < H_) ? 1.f : 0.f;
        float vy1 = (y0 + 1 >= 0 && y0 + 1 < H_) ? 1.f : 0.f;
        float vx0 = (x0     >= 0 && x0     < W_) ? 1.f : 0.f;
        float vx1 = (x0 + 1 >= 0 && x0 + 1 < W_) ? 1.f : 0.f;
        wgtv[i] = make_float4((1.f - fy) * (1.f - fx) * vy0 * vx0 * md,
                              (1.f - fy) * fx         * vy0 * vx1 * md,
                              fy         * (1.f - fx) * vy1 * vx0 * md,
                              fy         * fx         * vy1 * vx1 * md);
        const int rowb = (b * HW_) * (C_ * 2);       // byte offset of batch b in xT
        idxv[i] = make_int4(rowb + (y0c * W_ + x0c) * (C_ * 2),
                            rowb + (y0c * W_ + x1c) * (C_ * 2),
                            rowb + (y1c * W_ + x0c) * (C_ * 2),
                            rowb + (y1c * W_ + x1c) * (C_ * 2));
    }
    __syncthreads();                      // tables visible; omb dead (Abuf may overwrite)

    // ================= Phase B: sample + GEMM =================
    f32x4 acc[4][2];
#pragma unroll
    for (int mi = 0; mi < 4; ++mi)
#pragma unroll
        for (int nj = 0; nj < 2; ++nj)
#pragma unroll
            for (int r = 0; r < 4; ++r) acc[mi][nj][r] = 0.f;

    const uint4* wKf4 = (const uint4*)wKf;
    const char*  xTb  = (const char*)xT;

    // sampling write-dest precompute (lane covers channels 4*lane .. 4*lane+3)
    const int s_cc = lane >> 3;                   // 32-ch chunk
    const int s_q2 = (lane >> 1) & 3;             // k-quad within chunk
    const int s_j0 = (lane & 1) * 4;              // element offset within frag row
    const int s_xr = (s_q2 << 1) ^ s_cc;          // XOR swizzle for bank spread
    const int s_mi = wv >> 1;                     // m-tile this wave's pixels fall in
    const int s_pb = (wv & 1) * 8;                // pixel base within m-tile
    const int loff = lane * 8;                    // byte offset within 512-B pixel row

    const int r_row = lane ^ ((lane >> 4) << 1);  // MFMA-side read row (pre-XOR by cc)

    for (int tap = 0; tap < 9; ++tap) {
        // ---- sample 8 pixels: coalesced 512-B corner loads, weighted sum ----
        uint2 pk[8];
#pragma unroll
        for (int pp = 0; pp < 8; ++pp) {
            const int p = wv * 8 + pp;
            const int4   iq = idxv[p * 9 + tap];
            const float4 wq = wgtv[p * 9 + tap];
            const uint2 k0 = *(const uint2*)(xTb + iq.x + loff);
            const uint2 k1 = *(const uint2*)(xTb + iq.y + loff);
            const uint2 k2 = *(const uint2*)(xTb + iq.z + loff);
            const uint2 k3 = *(const uint2*)(xTb + iq.w + loff);
            float g0 = wq.x*bflo(k0.x) + wq.y*bflo(k1.x) + wq.z*bflo(k2.x) + wq.w*bflo(k3.x);
            float g1 = wq.x*bfhi(k0.x) + wq.y*bfhi(k1.x) + wq.z*bfhi(k2.x) + wq.w*bfhi(k3.x);
            float g2 = wq.x*bflo(k0.y) + wq.y*bflo(k1.y) + wq.z*bflo(k2.y) + wq.w*bflo(k3.y);
            float g3 = wq.x*bfhi(k0.y) + wq.y*bfhi(k1.y) + wq.z*bfhi(k2.y) + wq.w*bfhi(k3.y);
            pk[pp].x = packbf2(g0, g1);
            pk[pp].y = packbf2(g2, g3);
        }

        __syncthreads();                  // previous tap's A-frag reads complete
#pragma unroll
        for (int pp = 0; pp < 8; ++pp) {
            const int P   = s_pb + pp;                     // pixel & 15
            const int row = (P ^ s_xr) | (s_q2 << 4);      // swizzled frag row
            *(uint2*)&Abuf[s_cc][s_mi][row][s_j0] = pk[pp];
        }
        __syncthreads();                  // tap's A tile visible

        // ---- MFMA: 8 K-steps of 32 channels ----
#pragma unroll
        for (int cc = 0; cc < 8; ++cc) {
            const int KC = tap * 8 + cc;
            const int rr = r_row ^ cc;
            uint4 braw[2];
#pragma unroll
            for (int nj = 0; nj < 2; ++nj)
                braw[nj] = wKf4[(size_t)((wv * 2 + nj) * 72 + KC) * 64 + lane];
            bf16x8 a[4];
#pragma unroll
            for (int mi = 0; mi < 4; ++mi)
                a[mi] = *(const bf16x8*)&Abuf[cc][mi][rr][0];
#pragma unroll
            for (int nj = 0; nj < 2; ++nj) {
                bf16x8 bb = __builtin_bit_cast(bf16x8, braw[nj]);
#pragma unroll
                for (int mi = 0; mi < 4; ++mi)
                    acc[mi][nj] = __builtin_amdgcn_mfma_f32_16x16x32_bf16(
                        a[mi], bb, acc[mi][nj], 0, 0, 0);
            }
        }
    }

    // ---- epilogue: conv bias + BN + ReLU, float4 stores ----
#pragma unroll
    for (int nj = 0; nj < 2; ++nj) {
        const int o = wv * 32 + nj * 16 + (lane & 15);
        const float inv = gamma[o] * rsqrtf(rvar[o] + BN_EPS);
        const float sh  = beta[o] + (bias[o] - rmean[o]) * inv;
        float* ob = out + ((size_t)(b * O_ + o)) * HW_ + h * W_;
#pragma unroll
        for (int mi = 0; mi < 4; ++mi) {
            f32x4 v = acc[mi][nj];
            float4 r;
            r.x = fmaxf(v[0] * inv + sh, 0.f);
            r.y = fmaxf(v[1] * inv + sh, 0.f);
            r.z = fmaxf(v[2] * inv + sh, 0.f);
            r.w = fmaxf(v[3] * inv + sh, 0.f);
            *(float4*)&ob[mi * 16 + (lane >> 4) * 4] = r;
        }
    }
}

extern "C" void kernel_launch(void* const* d_in, const int* in_sizes, int n_in,
                              void* d_out, int out_size, void* d_ws, size_t ws_size,
                              hipStream_t stream) {
    const float* x     = (const float*)d_in[0];
    const float* w_off = (const float*)d_in[1];
    const float* b_off = (const float*)d_in[2];
    const float* w     = (const float*)d_in[3];
    const float* bias  = (const float*)d_in[4];
    const float* gamma = (const float*)d_in[5];
    const float* beta  = (const float*)d_in[6];
    const float* rmean = (const float*)d_in[7];
    const float* rvar  = (const float*)d_in[8];
    float* out = (float*)d_out;

    unsigned short* xT  = (unsigned short*)d_ws;              // 8388608 bf16 (16 MB)
    unsigned short* wKf = xT + 8388608;                       // 589824 bf16
    unsigned short* wof = wKf + 589824;                       // 73728 bf16

    prep_kernel<<<2192, 256, 0, stream>>>(x, w, w_off, xT, wKf, wof);
    dcn_fused_kernel<<<512, 512, 0, stream>>>(
        xT, wKf, wof, b_off, bias, gamma, beta, rmean, rvar, out);
}